// Round 3
// baseline (575.073 us; speedup 1.0000x reference)
//
#include <hip/hip_runtime.h>
#include <hip/hip_bf16.h>

#define N_NODES 10000
#define N_EDGES 80000
#define FN 16
#define FE 8
#define HID 25
#define C1 32
#define C2 64
#define NU_BLOCKS 256
#define FC_BLOCKS 640

__device__ __forceinline__ float elu_f(float x) { return x > 0.f ? x : (expf(x) - 1.f); }

// --- K1: per-edge hidden layer for both convs: relu(ea@w1+b1), plus degree count.
//         hr stored TRANSPOSED [HID][E] so writes are coalesced. ---
__global__ void k_edge_hidden(const float* __restrict__ ea, const int* __restrict__ ei,
                              const float* __restrict__ w1a, const float* __restrict__ b1a,
                              const float* __restrict__ w1b, const float* __restrict__ b1b,
                              float* __restrict__ hr1, float* __restrict__ hr2,
                              float* __restrict__ deg) {
    __shared__ float sw1a[FE * HID], sw1b[FE * HID], sb1a[HID], sb1b[HID];
    int tid = threadIdx.x;
    for (int i = tid; i < FE * HID; i += blockDim.x) { sw1a[i] = w1a[i]; sw1b[i] = w1b[i]; }
    if (tid < HID) { sb1a[tid] = b1a[tid]; sb1b[tid] = b1b[tid]; }
    __syncthreads();
    int e = blockIdx.x * blockDim.x + tid;
    if (e >= N_EDGES) return;
    float a[FE];
#pragma unroll
    for (int i = 0; i < FE; i++) a[i] = ea[e * FE + i];
#pragma unroll
    for (int k = 0; k < HID; k++) {
        float s1 = sb1a[k], s2 = sb1b[k];
#pragma unroll
        for (int i = 0; i < FE; i++) { s1 += a[i] * sw1a[i * HID + k]; s2 += a[i] * sw1b[i * HID + k]; }
        hr1[k * N_EDGES + e] = fmaxf(s1, 0.f);
        hr2[k * N_EDGES + e] = fmaxf(s2, 0.f);
    }
    atomicAdd(&deg[ei[N_EDGES + e]], 1.0f);
}

// --- K2: per-node precompute, GEMM-style. P[n, k*COUT+o] = sum_i x[n,i]*w2[k,i,o]
//         for k<HID; row k==HID holds the b2 term: sum_i x[n,i]*b2[i,o].
//         TN nodes/block amortize the w2 read (L2 traffic /TN). ---
template <int CIN, int COUT>
__global__ void k_precompute_P(const float* __restrict__ xin, const float* __restrict__ w2,
                               const float* __restrict__ b2, float* __restrict__ P) {
    constexpr int TN = 16;
    constexpr int M = (HID + 1) * COUT;
    __shared__ float xs[TN * CIN];
    int tid = threadIdx.x;
    int node0 = blockIdx.x * TN;
    for (int i = tid; i < TN * CIN; i += 256) xs[i] = xin[node0 * CIN + i];
    __syncthreads();
    for (int mb = 0; mb < M; mb += 256) {
        int m = mb + tid;
        if (m >= M) break;
        int k = m / COUT, o = m % COUT;
        float wreg[CIN];
        if (k < HID) {
#pragma unroll
            for (int i = 0; i < CIN; i++) wreg[i] = w2[(k * CIN + i) * COUT + o];
        } else {
#pragma unroll
            for (int i = 0; i < CIN; i++) wreg[i] = b2[i * COUT + o];
        }
#pragma unroll
        for (int n = 0; n < TN; n++) {
            const float* xr = &xs[n * CIN];  // wave-uniform -> LDS broadcast
            float s = 0.f;
#pragma unroll
            for (int i = 0; i < CIN; i++) s += xr[i] * wreg[i];
            P[(size_t)(node0 + n) * M + m] = s;
        }
    }
}

// --- K3: per-edge message msg[e,o] = P[src,HID,o] + sum_k hr[e,k]*P[src,k,o];
//         atomic scatter into agg[dst,o] (random dst -> low contention) ---
template <int COUT>
__global__ void k_edge_msg(const int* __restrict__ ei, const float* __restrict__ hr,
                           const float* __restrict__ P, float* __restrict__ agg) {
    int t = blockIdx.x * blockDim.x + threadIdx.x;
    int e = t / COUT, o = t % COUT;
    if (e >= N_EDGES) return;
    int src = ei[e], dst = ei[N_EDGES + e];
    const float* Pr = P + (size_t)src * ((HID + 1) * COUT) + o;
    float s = Pr[HID * COUT];  // b2 term
#pragma unroll
    for (int k = 0; k < HID; k++) s += hr[k * N_EDGES + e] * Pr[k * COUT];
    atomicAdd(&agg[dst * COUT + o], s);
}

// --- K4: node update: act = elu(x@root + agg/max(deg,1) + bias); BN sums via
//         per-thread register accumulation + 1 LDS reduce + 256 atomics/chan ---
template <int CIN, int COUT>
__global__ void k_node_update(const float* __restrict__ xin, const float* __restrict__ root,
                              const float* __restrict__ bias, const float* __restrict__ agg,
                              const float* __restrict__ deg, float* __restrict__ act,
                              float* __restrict__ s1g, float* __restrict__ s2g) {
    __shared__ float l1[256], l2[256];
    int tid = threadIdx.x;
    int o = tid % COUT;  // stride (NU_BLOCKS*256) % COUT == 0 -> channel invariant
    float b = bias[o];
    float rcol[CIN];
#pragma unroll
    for (int i = 0; i < CIN; i++) rcol[i] = root[i * COUT + o];
    float acc1 = 0.f, acc2 = 0.f;
    for (int t = blockIdx.x * 256 + tid; t < N_NODES * COUT; t += NU_BLOCKS * 256) {
        int n = t / COUT;
        float s = b;
        const float* xr = xin + n * CIN;
#pragma unroll
        for (int i = 0; i < CIN; i++) s += xr[i] * rcol[i];
        s += agg[t] / fmaxf(deg[n], 1.0f);
        float a = elu_f(s);
        act[t] = a;
        acc1 += a; acc2 += a * a;
    }
    l1[tid] = acc1; l2[tid] = acc2;
    __syncthreads();
    for (int s = 128; s >= COUT; s >>= 1) {
        if (tid < s) { l1[tid] += l1[tid + s]; l2[tid] += l2[tid + s]; }
        __syncthreads();
    }
    if (tid < COUT) { atomicAdd(&s1g[tid], l1[tid]); atomicAdd(&s2g[tid], l2[tid]); }
}

// --- K5: batchnorm (training stats) + elu ---
template <int COUT>
__global__ void k_bn_elu(const float* __restrict__ act, const float* __restrict__ s1g,
                         const float* __restrict__ s2g, const float* __restrict__ gamma,
                         const float* __restrict__ beta, float* __restrict__ out) {
    int t = blockIdx.x * blockDim.x + threadIdx.x;
    if (t >= N_NODES * COUT) return;
    int o = t % COUT;
    float m = s1g[o] * (1.0f / N_NODES);
    float v = s2g[o] * (1.0f / N_NODES) - m * m;
    float x = (act[t] - m) * rsqrtf(v + 1e-5f) * gamma[o] + beta[o];
    out[t] = elu_f(x);
}

// --- K6: fc1 (64->128) + elu + fc2 (128->1) + elu + per-block partial sums.
//         One node per wave: lane j handles fc1 outputs j and j+64; shuffle reduce. ---
__global__ void k_fc_sum(const float* __restrict__ h2, const float* __restrict__ fc1w,
                         const float* __restrict__ fc1b, const float* __restrict__ fc2w,
                         const float* __restrict__ fc2b, float* __restrict__ partial) {
    int tid = threadIdx.x;
    int lane = tid & 63;
    int wave = tid >> 6;
    float b0 = fc1b[lane], b1 = fc1b[lane + 64];
    float w0 = fc2w[lane], w1 = fc2w[lane + 64];
    float fb = fc2b[0];
    float acc = 0.f;
    for (int n = blockIdx.x * 4 + wave; n < N_NODES; n += FC_BLOCKS * 4) {
        const float* hr = h2 + n * C2;
        float s0 = b0, s1 = b1;
#pragma unroll
        for (int i = 0; i < C2; i++) {
            float hv = hr[i];  // broadcast within wave
            s0 += hv * fc1w[i * 128 + lane];
            s1 += hv * fc1w[i * 128 + 64 + lane];
        }
        float v = elu_f(s0) * w0 + elu_f(s1) * w1;
#pragma unroll
        for (int off = 32; off > 0; off >>= 1) v += __shfl_down(v, off);
        if (lane == 0) acc += elu_f(v + fb);
    }
    __shared__ float lds[4];
    if (lane == 0) lds[wave] = acc;
    __syncthreads();
    if (tid == 0) partial[blockIdx.x] = lds[0] + lds[1] + lds[2] + lds[3];
}

// --- K7: final reduction of FC_BLOCKS partials -> out[0] ---
__global__ void k_fc_reduce(const float* __restrict__ partial, float* __restrict__ out) {
    __shared__ float lds[256];
    int tid = threadIdx.x;
    float s = 0.f;
    for (int i = tid; i < FC_BLOCKS; i += 256) s += partial[i];
    lds[tid] = s;
    __syncthreads();
    for (int k = 128; k > 0; k >>= 1) {
        if (tid < k) lds[tid] += lds[tid + k];
        __syncthreads();
    }
    if (tid == 0) out[0] = lds[0];
}

extern "C" void kernel_launch(void* const* d_in, const int* in_sizes, int n_in,
                              void* d_out, int out_size, void* d_ws, size_t ws_size,
                              hipStream_t stream) {
    const float* x        = (const float*)d_in[0];
    const int*   ei       = (const int*)d_in[1];
    const float* ea       = (const float*)d_in[2];
    const float* nn1_w1   = (const float*)d_in[3];
    const float* nn1_b1   = (const float*)d_in[4];
    const float* nn1_w2   = (const float*)d_in[5];
    const float* nn1_b2   = (const float*)d_in[6];
    const float* c1_root  = (const float*)d_in[7];
    const float* c1_bias  = (const float*)d_in[8];
    const float* bn1_g    = (const float*)d_in[9];
    const float* bn1_b    = (const float*)d_in[10];
    const float* nn2_w1   = (const float*)d_in[11];
    const float* nn2_b1   = (const float*)d_in[12];
    const float* nn2_w2   = (const float*)d_in[13];
    const float* nn2_b2   = (const float*)d_in[14];
    const float* c2_root  = (const float*)d_in[15];
    const float* c2_bias  = (const float*)d_in[16];
    const float* bn2_g    = (const float*)d_in[17];
    const float* bn2_b    = (const float*)d_in[18];
    const float* fc1_w    = (const float*)d_in[19];
    const float* fc1_b    = (const float*)d_in[20];
    const float* fc2_w    = (const float*)d_in[21];
    const float* fc2_b    = (const float*)d_in[22];
    float* out = (float*)d_out;

    char* ws = (char*)d_ws;
    size_t off = 0;
    auto alloc = [&](size_t nfloats) -> float* {
        float* p = (float*)(ws + off);
        off += nfloats * sizeof(float);
        off = (off + 255) & ~(size_t)255;
        return p;
    };
    // zeroed region (deg, agg1, agg2, BN sums) must be contiguous & first
    float* deg    = alloc(N_NODES);
    float* agg1   = alloc((size_t)N_NODES * C1);
    float* agg2   = alloc((size_t)N_NODES * C2);
    float* bn1_s1 = alloc(C1);
    float* bn1_s2 = alloc(C1);
    float* bn2_s1 = alloc(C2);
    float* bn2_s2 = alloc(C2);
    size_t zero_bytes = off;
    float* hr1 = alloc((size_t)N_EDGES * HID);
    float* hr2 = alloc((size_t)N_EDGES * HID);
    float* P1  = alloc((size_t)N_NODES * (HID + 1) * C1);
    float* P2  = alloc((size_t)N_NODES * (HID + 1) * C2);
    float* a1  = alloc((size_t)N_NODES * C1);
    float* h1  = alloc((size_t)N_NODES * C1);
    float* a2  = alloc((size_t)N_NODES * C2);
    float* h2  = alloc((size_t)N_NODES * C2);
    float* partial = alloc(FC_BLOCKS);
    (void)ws_size;

    hipMemsetAsync(d_ws, 0, zero_bytes, stream);

    // edge hidden layers (both convs) + degrees
    k_edge_hidden<<<(N_EDGES + 255) / 256, 256, 0, stream>>>(ea, ei, nn1_w1, nn1_b1,
                                                             nn2_w1, nn2_b1, hr1, hr2, deg);
    // ---- conv1 ----
    k_precompute_P<FN, C1><<<N_NODES / 16, 256, 0, stream>>>(x, nn1_w2, nn1_b2, P1);
    k_edge_msg<C1><<<(N_EDGES * C1) / 256, 256, 0, stream>>>(ei, hr1, P1, agg1);
    k_node_update<FN, C1><<<NU_BLOCKS, 256, 0, stream>>>(x, c1_root, c1_bias, agg1,
                                                         deg, a1, bn1_s1, bn1_s2);
    k_bn_elu<C1><<<(N_NODES * C1) / 256, 256, 0, stream>>>(a1, bn1_s1, bn1_s2, bn1_g, bn1_b, h1);
    // ---- conv2 ----
    k_precompute_P<C1, C2><<<N_NODES / 16, 256, 0, stream>>>(h1, nn2_w2, nn2_b2, P2);
    k_edge_msg<C2><<<(N_EDGES * C2) / 256, 256, 0, stream>>>(ei, hr2, P2, agg2);
    k_node_update<C1, C2><<<NU_BLOCKS, 256, 0, stream>>>(h1, c2_root, c2_bias, agg2,
                                                         deg, a2, bn2_s1, bn2_s2);
    k_bn_elu<C2><<<(N_NODES * C2) / 256, 256, 0, stream>>>(a2, bn2_s1, bn2_s2, bn2_g, bn2_b, h2);
    // ---- fc + global sum ----
    k_fc_sum<<<FC_BLOCKS, 256, 0, stream>>>(h2, fc1_w, fc1_b, fc2_w, fc2_b, partial);
    k_fc_reduce<<<1, 256, 0, stream>>>(partial, out);
}

// Round 4
// 483.652 us; speedup vs baseline: 1.1890x; 1.1890x over previous
//
#include <hip/hip_runtime.h>
#include <hip/hip_bf16.h>

#define N_NODES 10000
#define N_EDGES 80000
#define FN 16
#define FE 8
#define HID 25
#define C1 32
#define C2 64
#define NU_BLOCKS 256
#define FC_BLOCKS 640

__device__ __forceinline__ float elu_f(float x) { return x > 0.f ? x : (expf(x) - 1.f); }

// --- K1: per-edge hidden layer for both convs: relu(ea@w1+b1), plus degree count.
//         hr stored TRANSPOSED [HID][E] so writes are coalesced. ---
__global__ void k_edge_hidden(const float* __restrict__ ea, const int* __restrict__ ei,
                              const float* __restrict__ w1a, const float* __restrict__ b1a,
                              const float* __restrict__ w1b, const float* __restrict__ b1b,
                              float* __restrict__ hr1, float* __restrict__ hr2,
                              float* __restrict__ deg) {
    __shared__ float sw1a[FE * HID], sw1b[FE * HID], sb1a[HID], sb1b[HID];
    int tid = threadIdx.x;
    for (int i = tid; i < FE * HID; i += blockDim.x) { sw1a[i] = w1a[i]; sw1b[i] = w1b[i]; }
    if (tid < HID) { sb1a[tid] = b1a[tid]; sb1b[tid] = b1b[tid]; }
    __syncthreads();
    int e = blockIdx.x * blockDim.x + tid;
    if (e >= N_EDGES) return;
    float a[FE];
#pragma unroll
    for (int i = 0; i < FE; i++) a[i] = ea[e * FE + i];
#pragma unroll
    for (int k = 0; k < HID; k++) {
        float s1 = sb1a[k], s2 = sb1b[k];
#pragma unroll
        for (int i = 0; i < FE; i++) { s1 += a[i] * sw1a[i * HID + k]; s2 += a[i] * sw1b[i * HID + k]; }
        hr1[k * N_EDGES + e] = fmaxf(s1, 0.f);
        hr2[k * N_EDGES + e] = fmaxf(s2, 0.f);
    }
    atomicAdd(&deg[ei[N_EDGES + e]], 1.0f);
}

// --- K2: per-node precompute. P[n, k*COUT+o] = sum_i x[n,i]*w2[k,i,o] for k<HID;
//         row k==HID holds the b2 term. R2-proven loop shape (ko-strided, w2 value
//         loaded once -> applied immediately), TN=4 nodes/block to cut w2 L2
//         traffic 4x while keeping 2500 blocks resident. ---
template <int CIN, int COUT>
__global__ void k_precompute_P(const float* __restrict__ xin, const float* __restrict__ w2,
                               const float* __restrict__ b2, float* __restrict__ P) {
    constexpr int TN = 4;
    constexpr int M = (HID + 1) * COUT;
    __shared__ float xs[TN * CIN];
    int tid = threadIdx.x;
    int node0 = blockIdx.x * TN;
    for (int i = tid; i < TN * CIN; i += 256) xs[i] = xin[node0 * CIN + i];
    __syncthreads();
    for (int ko = tid; ko < M; ko += 256) {
        int k = ko / COUT, o = ko % COUT;
        const float* wr = (k < HID) ? (w2 + (size_t)(k * CIN) * COUT + o) : (b2 + o);
        float s0 = 0.f, s1 = 0.f, s2 = 0.f, s3 = 0.f;
#pragma unroll
        for (int i = 0; i < CIN; i++) {
            float wv = wr[i * COUT];
            s0 += xs[i] * wv;
            s1 += xs[CIN + i] * wv;
            s2 += xs[2 * CIN + i] * wv;
            s3 += xs[3 * CIN + i] * wv;
        }
        size_t base = (size_t)node0 * M + ko;
        P[base] = s0;
        P[base + M] = s1;
        P[base + 2 * M] = s2;
        P[base + 3 * M] = s3;
    }
}

// --- K3: per-edge message msg[e,o] = P[src,HID,o] + sum_k hr[e,k]*P[src,k,o];
//         atomic scatter into agg[dst,o] (random dst -> low contention) ---
template <int COUT>
__global__ void k_edge_msg(const int* __restrict__ ei, const float* __restrict__ hr,
                           const float* __restrict__ P, float* __restrict__ agg) {
    int t = blockIdx.x * blockDim.x + threadIdx.x;
    int e = t / COUT, o = t % COUT;
    if (e >= N_EDGES) return;
    int src = ei[e], dst = ei[N_EDGES + e];
    const float* Pr = P + (size_t)src * ((HID + 1) * COUT) + o;
    float s = Pr[HID * COUT];  // b2 term
#pragma unroll
    for (int k = 0; k < HID; k++) s += hr[k * N_EDGES + e] * Pr[k * COUT];
    atomicAdd(&agg[dst * COUT + o], s);
}

// --- K4: node update: act = elu(x@root + agg/max(deg,1) + bias); BN sums via
//         per-thread register accumulation + 1 LDS reduce + 256 atomics/chan ---
template <int CIN, int COUT>
__global__ void k_node_update(const float* __restrict__ xin, const float* __restrict__ root,
                              const float* __restrict__ bias, const float* __restrict__ agg,
                              const float* __restrict__ deg, float* __restrict__ act,
                              float* __restrict__ s1g, float* __restrict__ s2g) {
    __shared__ float l1[256], l2[256];
    int tid = threadIdx.x;
    int o = tid % COUT;  // stride (NU_BLOCKS*256) % COUT == 0 -> channel invariant
    float b = bias[o];
    float rcol[CIN];
#pragma unroll
    for (int i = 0; i < CIN; i++) rcol[i] = root[i * COUT + o];
    float acc1 = 0.f, acc2 = 0.f;
    for (int t = blockIdx.x * 256 + tid; t < N_NODES * COUT; t += NU_BLOCKS * 256) {
        int n = t / COUT;
        float s = b;
        const float* xr = xin + n * CIN;
#pragma unroll
        for (int i = 0; i < CIN; i++) s += xr[i] * rcol[i];
        s += agg[t] / fmaxf(deg[n], 1.0f);
        float a = elu_f(s);
        act[t] = a;
        acc1 += a; acc2 += a * a;
    }
    l1[tid] = acc1; l2[tid] = acc2;
    __syncthreads();
    for (int s = 128; s >= COUT; s >>= 1) {
        if (tid < s) { l1[tid] += l1[tid + s]; l2[tid] += l2[tid + s]; }
        __syncthreads();
    }
    if (tid < COUT) { atomicAdd(&s1g[tid], l1[tid]); atomicAdd(&s2g[tid], l2[tid]); }
}

// --- K5: batchnorm (training stats) + elu ---
template <int COUT>
__global__ void k_bn_elu(const float* __restrict__ act, const float* __restrict__ s1g,
                         const float* __restrict__ s2g, const float* __restrict__ gamma,
                         const float* __restrict__ beta, float* __restrict__ out) {
    int t = blockIdx.x * blockDim.x + threadIdx.x;
    if (t >= N_NODES * COUT) return;
    int o = t % COUT;
    float m = s1g[o] * (1.0f / N_NODES);
    float v = s2g[o] * (1.0f / N_NODES) - m * m;
    float x = (act[t] - m) * rsqrtf(v + 1e-5f) * gamma[o] + beta[o];
    out[t] = elu_f(x);
}

// --- K6: fc1 (64->128) + elu + fc2 (128->1) + elu + per-block partial sums.
//         One node per wave: lane j handles fc1 outputs j and j+64; shuffle reduce. ---
__global__ void k_fc_sum(const float* __restrict__ h2, const float* __restrict__ fc1w,
                         const float* __restrict__ fc1b, const float* __restrict__ fc2w,
                         const float* __restrict__ fc2b, float* __restrict__ partial) {
    int tid = threadIdx.x;
    int lane = tid & 63;
    int wave = tid >> 6;
    float b0 = fc1b[lane], b1 = fc1b[lane + 64];
    float w0 = fc2w[lane], w1 = fc2w[lane + 64];
    float fb = fc2b[0];
    float acc = 0.f;
    for (int n = blockIdx.x * 4 + wave; n < N_NODES; n += FC_BLOCKS * 4) {
        const float* hr = h2 + n * C2;
        float s0 = b0, s1 = b1;
#pragma unroll
        for (int i = 0; i < C2; i++) {
            float hv = hr[i];  // broadcast within wave
            s0 += hv * fc1w[i * 128 + lane];
            s1 += hv * fc1w[i * 128 + 64 + lane];
        }
        float v = elu_f(s0) * w0 + elu_f(s1) * w1;
#pragma unroll
        for (int off = 32; off > 0; off >>= 1) v += __shfl_down(v, off);
        if (lane == 0) acc += elu_f(v + fb);
    }
    __shared__ float lds[4];
    if (lane == 0) lds[wave] = acc;
    __syncthreads();
    if (tid == 0) partial[blockIdx.x] = lds[0] + lds[1] + lds[2] + lds[3];
}

// --- K7: final reduction of FC_BLOCKS partials -> out[0] ---
__global__ void k_fc_reduce(const float* __restrict__ partial, float* __restrict__ out) {
    __shared__ float lds[256];
    int tid = threadIdx.x;
    float s = 0.f;
    for (int i = tid; i < FC_BLOCKS; i += 256) s += partial[i];
    lds[tid] = s;
    __syncthreads();
    for (int k = 128; k > 0; k >>= 1) {
        if (tid < k) lds[tid] += lds[tid + k];
        __syncthreads();
    }
    if (tid == 0) out[0] = lds[0];
}

extern "C" void kernel_launch(void* const* d_in, const int* in_sizes, int n_in,
                              void* d_out, int out_size, void* d_ws, size_t ws_size,
                              hipStream_t stream) {
    const float* x        = (const float*)d_in[0];
    const int*   ei       = (const int*)d_in[1];
    const float* ea       = (const float*)d_in[2];
    const float* nn1_w1   = (const float*)d_in[3];
    const float* nn1_b1   = (const float*)d_in[4];
    const float* nn1_w2   = (const float*)d_in[5];
    const float* nn1_b2   = (const float*)d_in[6];
    const float* c1_root  = (const float*)d_in[7];
    const float* c1_bias  = (const float*)d_in[8];
    const float* bn1_g    = (const float*)d_in[9];
    const float* bn1_b    = (const float*)d_in[10];
    const float* nn2_w1   = (const float*)d_in[11];
    const float* nn2_b1   = (const float*)d_in[12];
    const float* nn2_w2   = (const float*)d_in[13];
    const float* nn2_b2   = (const float*)d_in[14];
    const float* c2_root  = (const float*)d_in[15];
    const float* c2_bias  = (const float*)d_in[16];
    const float* bn2_g    = (const float*)d_in[17];
    const float* bn2_b    = (const float*)d_in[18];
    const float* fc1_w    = (const float*)d_in[19];
    const float* fc1_b    = (const float*)d_in[20];
    const float* fc2_w    = (const float*)d_in[21];
    const float* fc2_b    = (const float*)d_in[22];
    float* out = (float*)d_out;

    char* ws = (char*)d_ws;
    size_t off = 0;
    auto alloc = [&](size_t nfloats) -> float* {
        float* p = (float*)(ws + off);
        off += nfloats * sizeof(float);
        off = (off + 255) & ~(size_t)255;
        return p;
    };
    // zeroed region (deg, agg1, agg2, BN sums) must be contiguous & first
    float* deg    = alloc(N_NODES);
    float* agg1   = alloc((size_t)N_NODES * C1);
    float* agg2   = alloc((size_t)N_NODES * C2);
    float* bn1_s1 = alloc(C1);
    float* bn1_s2 = alloc(C1);
    float* bn2_s1 = alloc(C2);
    float* bn2_s2 = alloc(C2);
    size_t zero_bytes = off;
    float* hr1 = alloc((size_t)N_EDGES * HID);
    float* hr2 = alloc((size_t)N_EDGES * HID);
    float* P1  = alloc((size_t)N_NODES * (HID + 1) * C1);
    float* P2  = alloc((size_t)N_NODES * (HID + 1) * C2);
    float* a1  = alloc((size_t)N_NODES * C1);
    float* h1  = alloc((size_t)N_NODES * C1);
    float* a2  = alloc((size_t)N_NODES * C2);
    float* h2  = alloc((size_t)N_NODES * C2);
    float* partial = alloc(FC_BLOCKS);
    (void)ws_size;

    hipMemsetAsync(d_ws, 0, zero_bytes, stream);

    // edge hidden layers (both convs) + degrees
    k_edge_hidden<<<(N_EDGES + 255) / 256, 256, 0, stream>>>(ea, ei, nn1_w1, nn1_b1,
                                                             nn2_w1, nn2_b1, hr1, hr2, deg);
    // ---- conv1 ----
    k_precompute_P<FN, C1><<<N_NODES / 4, 256, 0, stream>>>(x, nn1_w2, nn1_b2, P1);
    k_edge_msg<C1><<<(N_EDGES * C1) / 256, 256, 0, stream>>>(ei, hr1, P1, agg1);
    k_node_update<FN, C1><<<NU_BLOCKS, 256, 0, stream>>>(x, c1_root, c1_bias, agg1,
                                                         deg, a1, bn1_s1, bn1_s2);
    k_bn_elu<C1><<<(N_NODES * C1) / 256, 256, 0, stream>>>(a1, bn1_s1, bn1_s2, bn1_g, bn1_b, h1);
    // ---- conv2 ----
    k_precompute_P<C1, C2><<<N_NODES / 4, 256, 0, stream>>>(h1, nn2_w2, nn2_b2, P2);
    k_edge_msg<C2><<<(N_EDGES * C2) / 256, 256, 0, stream>>>(ei, hr2, P2, agg2);
    k_node_update<C1, C2><<<NU_BLOCKS, 256, 0, stream>>>(h1, c2_root, c2_bias, agg2,
                                                         deg, a2, bn2_s1, bn2_s2);
    k_bn_elu<C2><<<(N_NODES * C2) / 256, 256, 0, stream>>>(a2, bn2_s1, bn2_s2, bn2_g, bn2_b, h2);
    // ---- fc + global sum ----
    k_fc_sum<<<FC_BLOCKS, 256, 0, stream>>>(h2, fc1_w, fc1_b, fc2_w, fc2_b, partial);
    k_fc_reduce<<<1, 256, 0, stream>>>(partial, out);
}

// Round 5
// 392.850 us; speedup vs baseline: 1.4638x; 1.2311x over previous
//
#include <hip/hip_runtime.h>
#include <hip/hip_bf16.h>

#define N_NODES 10000
#define N_EDGES 80000
#define FN 16
#define FE 8
#define HID 25
#define C1 32
#define C2 64
#define NU_BLOCKS 256
#define FC_BLOCKS 640

__device__ __forceinline__ float elu_f(float x) { return x > 0.f ? x : (expf(x) - 1.f); }

// --- K1: per-edge hidden layer for both convs: relu(ea@w1+b1), plus degree count.
//         hr stored TRANSPOSED [HID][E] so writes are coalesced. ---
__global__ void k_edge_hidden(const float* __restrict__ ea, const int* __restrict__ ei,
                              const float* __restrict__ w1a, const float* __restrict__ b1a,
                              const float* __restrict__ w1b, const float* __restrict__ b1b,
                              float* __restrict__ hr1, float* __restrict__ hr2,
                              float* __restrict__ deg) {
    __shared__ float sw1a[FE * HID], sw1b[FE * HID], sb1a[HID], sb1b[HID];
    int tid = threadIdx.x;
    for (int i = tid; i < FE * HID; i += blockDim.x) { sw1a[i] = w1a[i]; sw1b[i] = w1b[i]; }
    if (tid < HID) { sb1a[tid] = b1a[tid]; sb1b[tid] = b1b[tid]; }
    __syncthreads();
    int e = blockIdx.x * blockDim.x + tid;
    if (e >= N_EDGES) return;
    float a[FE];
#pragma unroll
    for (int i = 0; i < FE; i++) a[i] = ea[e * FE + i];
#pragma unroll
    for (int k = 0; k < HID; k++) {
        float s1 = sb1a[k], s2 = sb1b[k];
#pragma unroll
        for (int i = 0; i < FE; i++) { s1 += a[i] * sw1a[i * HID + k]; s2 += a[i] * sw1b[i * HID + k]; }
        hr1[k * N_EDGES + e] = fmaxf(s1, 0.f);
        hr2[k * N_EDGES + e] = fmaxf(s2, 0.f);
    }
    atomicAdd(&deg[ei[N_EDGES + e]], 1.0f);
}

// --- K2a (R2-proven shape): one node per block. P[n,ko] = sum_i xn[i]*wcat[k,i,o].
//         wcat = [w2 | b2] concatenated, so no branch. xs is loop-invariant ->
//         compiler promotes all CIN LDS reads to registers; inner loop is
//         load->FMA only. ---
template <int CIN, int COUT>
__global__ void k_precompute_R2(const float* __restrict__ xin, const float* __restrict__ wcat,
                                float* __restrict__ P) {
    constexpr int M = (HID + 1) * COUT;
    __shared__ float xn[CIN];
    int n = blockIdx.x;
    int tid = threadIdx.x;
    if (tid < CIN) xn[tid] = xin[n * CIN + tid];
    __syncthreads();
    for (int ko = tid; ko < M; ko += 256) {
        int k = ko / COUT, o = ko % COUT;
        float s = 0.f;
#pragma unroll
        for (int i = 0; i < CIN; i++) s += xn[i] * wcat[k * (CIN * COUT) + i * COUT + o];
        P[(size_t)n * M + ko] = s;
    }
}

// --- K2b (m-major experiment): thread owns one output column wreg[CIN] (loaded
//         ONCE from L2; total w2 traffic ~13 MB), iterates TNODES LDS-broadcast
//         nodes. Grid = m-chunks x node-chunks. ---
template <int CIN, int COUT, int TNODES>
__global__ void k_precompute_mmajor(const float* __restrict__ xin, const float* __restrict__ wcat,
                                    float* __restrict__ P) {
    constexpr int M = (HID + 1) * COUT;
    constexpr int MB = (M + 255) / 256;
    __shared__ float xs[TNODES * CIN];
    int tid = threadIdx.x;
    int mb = blockIdx.x % MB;
    int n0 = (blockIdx.x / MB) * TNODES;
    for (int i = tid; i < TNODES * CIN; i += 256) xs[i] = xin[n0 * CIN + i];
    __syncthreads();
    int m = mb * 256 + tid;
    if (m >= M) return;
    int k = m / COUT, o = m % COUT;
    float wreg[CIN];
#pragma unroll
    for (int i = 0; i < CIN; i++) wreg[i] = wcat[k * (CIN * COUT) + i * COUT + o];
#pragma unroll 2
    for (int n = 0; n < TNODES; n++) {
        float s = 0.f;
#pragma unroll
        for (int i = 0; i < CIN; i++) s += xs[n * CIN + i] * wreg[i];
        P[(size_t)(n0 + n) * M + m] = s;
    }
}

// --- K3: per-edge message msg[e,o] = P[src,HID,o] + sum_k hr[e,k]*P[src,k,o];
//         atomic scatter into agg[dst,o] (random dst -> low contention) ---
template <int COUT>
__global__ void k_edge_msg(const int* __restrict__ ei, const float* __restrict__ hr,
                           const float* __restrict__ P, float* __restrict__ agg) {
    int t = blockIdx.x * blockDim.x + threadIdx.x;
    int e = t / COUT, o = t % COUT;
    if (e >= N_EDGES) return;
    int src = ei[e], dst = ei[N_EDGES + e];
    const float* Pr = P + (size_t)src * ((HID + 1) * COUT) + o;
    float s = Pr[HID * COUT];  // b2 term
#pragma unroll
    for (int k = 0; k < HID; k++) s += hr[k * N_EDGES + e] * Pr[k * COUT];
    atomicAdd(&agg[dst * COUT + o], s);
}

// --- K4: node update: act = elu(x@root + agg/max(deg,1) + bias); BN sums via
//         per-thread register accumulation + 1 LDS reduce + 256 atomics/chan ---
template <int CIN, int COUT>
__global__ void k_node_update(const float* __restrict__ xin, const float* __restrict__ root,
                              const float* __restrict__ bias, const float* __restrict__ agg,
                              const float* __restrict__ deg, float* __restrict__ act,
                              float* __restrict__ s1g, float* __restrict__ s2g) {
    __shared__ float l1[256], l2[256];
    int tid = threadIdx.x;
    int o = tid % COUT;  // stride (NU_BLOCKS*256) % COUT == 0 -> channel invariant
    float b = bias[o];
    float rcol[CIN];
#pragma unroll
    for (int i = 0; i < CIN; i++) rcol[i] = root[i * COUT + o];
    float acc1 = 0.f, acc2 = 0.f;
    for (int t = blockIdx.x * 256 + tid; t < N_NODES * COUT; t += NU_BLOCKS * 256) {
        int n = t / COUT;
        float s = b;
        const float* xr = xin + n * CIN;
#pragma unroll
        for (int i = 0; i < CIN; i++) s += xr[i] * rcol[i];
        s += agg[t] / fmaxf(deg[n], 1.0f);
        float a = elu_f(s);
        act[t] = a;
        acc1 += a; acc2 += a * a;
    }
    l1[tid] = acc1; l2[tid] = acc2;
    __syncthreads();
    for (int s = 128; s >= COUT; s >>= 1) {
        if (tid < s) { l1[tid] += l1[tid + s]; l2[tid] += l2[tid + s]; }
        __syncthreads();
    }
    if (tid < COUT) { atomicAdd(&s1g[tid], l1[tid]); atomicAdd(&s2g[tid], l2[tid]); }
}

// --- K5: batchnorm (training stats) + elu ---
template <int COUT>
__global__ void k_bn_elu(const float* __restrict__ act, const float* __restrict__ s1g,
                         const float* __restrict__ s2g, const float* __restrict__ gamma,
                         const float* __restrict__ beta, float* __restrict__ out) {
    int t = blockIdx.x * blockDim.x + threadIdx.x;
    if (t >= N_NODES * COUT) return;
    int o = t % COUT;
    float m = s1g[o] * (1.0f / N_NODES);
    float v = s2g[o] * (1.0f / N_NODES) - m * m;
    float x = (act[t] - m) * rsqrtf(v + 1e-5f) * gamma[o] + beta[o];
    out[t] = elu_f(x);
}

// --- K6: fc1 (64->128) + elu + fc2 (128->1) + elu + per-block partial sums. ---
__global__ void k_fc_sum(const float* __restrict__ h2, const float* __restrict__ fc1w,
                         const float* __restrict__ fc1b, const float* __restrict__ fc2w,
                         const float* __restrict__ fc2b, float* __restrict__ partial) {
    int tid = threadIdx.x;
    int lane = tid & 63;
    int wave = tid >> 6;
    float b0 = fc1b[lane], b1 = fc1b[lane + 64];
    float w0 = fc2w[lane], w1 = fc2w[lane + 64];
    float fb = fc2b[0];
    float acc = 0.f;
    for (int n = blockIdx.x * 4 + wave; n < N_NODES; n += FC_BLOCKS * 4) {
        const float* hr = h2 + n * C2;
        float s0 = b0, s1 = b1;
#pragma unroll
        for (int i = 0; i < C2; i++) {
            float hv = hr[i];  // broadcast within wave
            s0 += hv * fc1w[i * 128 + lane];
            s1 += hv * fc1w[i * 128 + 64 + lane];
        }
        float v = elu_f(s0) * w0 + elu_f(s1) * w1;
#pragma unroll
        for (int off = 32; off > 0; off >>= 1) v += __shfl_down(v, off);
        if (lane == 0) acc += elu_f(v + fb);
    }
    __shared__ float lds[4];
    if (lane == 0) lds[wave] = acc;
    __syncthreads();
    if (tid == 0) partial[blockIdx.x] = lds[0] + lds[1] + lds[2] + lds[3];
}

// --- K7: final reduction of FC_BLOCKS partials -> out[0] ---
__global__ void k_fc_reduce(const float* __restrict__ partial, float* __restrict__ out) {
    __shared__ float lds[256];
    int tid = threadIdx.x;
    float s = 0.f;
    for (int i = tid; i < FC_BLOCKS; i += 256) s += partial[i];
    lds[tid] = s;
    __syncthreads();
    for (int k = 128; k > 0; k >>= 1) {
        if (tid < k) lds[tid] += lds[tid + k];
        __syncthreads();
    }
    if (tid == 0) out[0] = lds[0];
}

extern "C" void kernel_launch(void* const* d_in, const int* in_sizes, int n_in,
                              void* d_out, int out_size, void* d_ws, size_t ws_size,
                              hipStream_t stream) {
    const float* x        = (const float*)d_in[0];
    const int*   ei       = (const int*)d_in[1];
    const float* ea       = (const float*)d_in[2];
    const float* nn1_w1   = (const float*)d_in[3];
    const float* nn1_b1   = (const float*)d_in[4];
    const float* nn1_w2   = (const float*)d_in[5];
    const float* nn1_b2   = (const float*)d_in[6];
    const float* c1_root  = (const float*)d_in[7];
    const float* c1_bias  = (const float*)d_in[8];
    const float* bn1_g    = (const float*)d_in[9];
    const float* bn1_b    = (const float*)d_in[10];
    const float* nn2_w1   = (const float*)d_in[11];
    const float* nn2_b1   = (const float*)d_in[12];
    const float* nn2_w2   = (const float*)d_in[13];
    const float* nn2_b2   = (const float*)d_in[14];
    const float* c2_root  = (const float*)d_in[15];
    const float* c2_bias  = (const float*)d_in[16];
    const float* bn2_g    = (const float*)d_in[17];
    const float* bn2_b    = (const float*)d_in[18];
    const float* fc1_w    = (const float*)d_in[19];
    const float* fc1_b    = (const float*)d_in[20];
    const float* fc2_w    = (const float*)d_in[21];
    const float* fc2_b    = (const float*)d_in[22];
    float* out = (float*)d_out;

    char* ws = (char*)d_ws;
    size_t off = 0;
    auto alloc = [&](size_t nfloats) -> float* {
        float* p = (float*)(ws + off);
        off += nfloats * sizeof(float);
        off = (off + 255) & ~(size_t)255;
        return p;
    };
    // zeroed region (deg, agg1, agg2, BN sums) must be contiguous & first
    float* deg    = alloc(N_NODES);
    float* agg1   = alloc((size_t)N_NODES * C1);
    float* agg2   = alloc((size_t)N_NODES * C2);
    float* bn1_s1 = alloc(C1);
    float* bn1_s2 = alloc(C1);
    float* bn2_s1 = alloc(C2);
    float* bn2_s2 = alloc(C2);
    size_t zero_bytes = off;
    float* hr1 = alloc((size_t)N_EDGES * HID);
    float* hr2 = alloc((size_t)N_EDGES * HID);
    float* P1  = alloc((size_t)N_NODES * (HID + 1) * C1);
    float* P2  = alloc((size_t)N_NODES * (HID + 1) * C2);
    float* a1  = alloc((size_t)N_NODES * C1);
    float* h1  = alloc((size_t)N_NODES * C1);
    float* a2  = alloc((size_t)N_NODES * C2);
    float* h2  = alloc((size_t)N_NODES * C2);
    float* partial = alloc(FC_BLOCKS);
    float* wcat1 = alloc((HID + 1) * FN * C1);
    float* wcat2 = alloc((HID + 1) * C1 * C2);
    (void)ws_size;

    hipMemsetAsync(d_ws, 0, zero_bytes, stream);
    // wcat = [w2 | b2] so precompute kernels are branch-free
    hipMemcpyAsync(wcat1, nn1_w2, sizeof(float) * HID * FN * C1, hipMemcpyDeviceToDevice, stream);
    hipMemcpyAsync(wcat1 + HID * FN * C1, nn1_b2, sizeof(float) * FN * C1, hipMemcpyDeviceToDevice, stream);
    hipMemcpyAsync(wcat2, nn2_w2, sizeof(float) * HID * C1 * C2, hipMemcpyDeviceToDevice, stream);
    hipMemcpyAsync(wcat2 + HID * C1 * C2, nn2_b2, sizeof(float) * C1 * C2, hipMemcpyDeviceToDevice, stream);

    // edge hidden layers (both convs) + degrees
    k_edge_hidden<<<(N_EDGES + 255) / 256, 256, 0, stream>>>(ea, ei, nn1_w1, nn1_b1,
                                                             nn2_w1, nn2_b1, hr1, hr2, deg);
    // ---- conv1 (m-major experimental precompute) ----
    k_precompute_mmajor<FN, C1, 50><<<(N_NODES / 50) * (((HID + 1) * C1 + 255) / 256), 256, 0, stream>>>(x, wcat1, P1);
    k_edge_msg<C1><<<(N_EDGES * C1) / 256, 256, 0, stream>>>(ei, hr1, P1, agg1);
    k_node_update<FN, C1><<<NU_BLOCKS, 256, 0, stream>>>(x, c1_root, c1_bias, agg1,
                                                         deg, a1, bn1_s1, bn1_s2);
    k_bn_elu<C1><<<(N_NODES * C1) / 256, 256, 0, stream>>>(a1, bn1_s1, bn1_s2, bn1_g, bn1_b, h1);
    // ---- conv2 (R2-proven precompute shape) ----
    k_precompute_R2<C1, C2><<<N_NODES, 256, 0, stream>>>(h1, wcat2, P2);
    k_edge_msg<C2><<<(N_EDGES * C2) / 256, 256, 0, stream>>>(ei, hr2, P2, agg2);
    k_node_update<C1, C2><<<NU_BLOCKS, 256, 0, stream>>>(h1, c2_root, c2_bias, agg2,
                                                         deg, a2, bn2_s1, bn2_s2);
    k_bn_elu<C2><<<(N_NODES * C2) / 256, 256, 0, stream>>>(a2, bn2_s1, bn2_s2, bn2_g, bn2_b, h2);
    // ---- fc + global sum ----
    k_fc_sum<<<FC_BLOCKS, 256, 0, stream>>>(h2, fc1_w, fc1_b, fc2_w, fc2_b, partial);
    k_fc_reduce<<<1, 256, 0, stream>>>(partial, out);
}

// Round 6
// 306.354 us; speedup vs baseline: 1.8771x; 1.2823x over previous
//
#include <hip/hip_runtime.h>
#include <hip/hip_bf16.h>

#define N_NODES 10000
#define N_EDGES 80000
#define FN 16
#define FE 8
#define HID 25
#define C1 32
#define C2 64
#define NU_BLOCKS 256
#define FC_BLOCKS 640

__device__ __forceinline__ float elu_f(float x) { return x > 0.f ? x : (expf(x) - 1.f); }

// --- K0a: int histogram of src (CSR build) and dst (mean-agg degree) ---
__global__ void k_count(const int* __restrict__ ei, int* __restrict__ cnt_src,
                        int* __restrict__ cnt_dst) {
    int e = blockIdx.x * 256 + threadIdx.x;
    if (e >= N_EDGES) return;
    atomicAdd(&cnt_src[ei[e]], 1);
    atomicAdd(&cnt_dst[ei[N_EDGES + e]], 1);
}

// --- K0b: exclusive prefix sum over cnt_src (10000) -> offs[10001], cursor copy.
//         One block, 1024 threads x 10 entries, two-level shuffle scan. ---
__global__ void k_scan(const int* __restrict__ cnt, int* __restrict__ offs,
                       int* __restrict__ cursor) {
    __shared__ int lws[16];
    int tid = threadIdx.x;
    int base = tid * 10;
    int loc[10];
    int s = 0;
#pragma unroll
    for (int j = 0; j < 10; j++) {
        loc[j] = s;
        int c = (base + j < N_NODES) ? cnt[base + j] : 0;
        s += c;
    }
    int lane = tid & 63, wv = tid >> 6;
    int v = s;
    for (int d = 1; d < 64; d <<= 1) {
        int t = __shfl_up(v, d);
        if (lane >= d) v += t;
    }
    if (lane == 63) lws[wv] = v;
    __syncthreads();
    if (tid < 64) {
        int w = (tid < 16) ? lws[tid] : 0;
        for (int d = 1; d < 16; d <<= 1) {
            int t = __shfl_up(w, d);
            if (tid >= d) w += t;
        }
        if (tid < 16) lws[tid] = w;
    }
    __syncthreads();
    int waveoff = (wv > 0) ? lws[wv - 1] : 0;
    int excl = waveoff + v - s;
#pragma unroll
    for (int j = 0; j < 10; j++) {
        int idx = base + j;
        if (idx < N_NODES) { int val = excl + loc[j]; offs[idx] = val; cursor[idx] = val; }
    }
    if (tid == 0) offs[N_NODES] = N_EDGES;
}

// --- K0c: scatter edges into src buckets; pack (e<<14 | dst), dst<16384 ---
__global__ void k_scatter(const int* __restrict__ ei, int* __restrict__ cursor,
                          int* __restrict__ ebuf) {
    int e = blockIdx.x * 256 + threadIdx.x;
    if (e >= N_EDGES) return;
    int src = ei[e], dst = ei[N_EDGES + e];
    int pos = atomicAdd(&cursor[src], 1);
    ebuf[pos] = (e << 14) | dst;
}

// --- K2: per-node precompute, m-major, NO LDS. Thread owns output column m:
//         wreg[CIN] loaded once (w2 L2 traffic ~13 MB total); x row read with
//         wave-uniform address (scalarizable); coalesced P stores.
//         P[n, k*COUT+o] = sum_i x[n,i]*wcat[k,i,o]; row k==HID is the b2 term. ---
template <int CIN, int COUT, int TNODES>
__global__ void k_precompute(const float* __restrict__ xin, const float* __restrict__ wcat,
                             float* __restrict__ P) {
    constexpr int M = (HID + 1) * COUT;
    constexpr int MB = (M + 255) / 256;
    int tid = threadIdx.x;
    int mb = blockIdx.x % MB;
    int n0 = (blockIdx.x / MB) * TNODES;
    int m = mb * 256 + tid;
    if (m >= M) return;
    int k = m / COUT, o = m % COUT;
    float wreg[CIN];
#pragma unroll
    for (int i = 0; i < CIN; i++) wreg[i] = wcat[(size_t)(k * CIN + i) * COUT + o];
    for (int n = n0; n < n0 + TNODES; n++) {
        const float* xr = xin + (size_t)n * CIN;  // wave-uniform address
        float s = 0.f;
#pragma unroll
        for (int i = 0; i < CIN; i++) s += xr[i] * wreg[i];
        P[(size_t)n * M + m] = s;
    }
}

// --- K3: grouped message pass. One 64/COUT-node wave-group per src node:
//         P row loaded once into regs (coalesced); per out-edge, edge-MLP hidden
//         computed in-register (lane k<25), broadcast via shfl, 26 FMA, 1 atomic. ---
template <int COUT>
__global__ void k_msg_grouped(const float* __restrict__ P, const float* __restrict__ ea,
                              const float* __restrict__ w1, const float* __restrict__ b1,
                              const int* __restrict__ offs, const int* __restrict__ ebuf,
                              float* __restrict__ agg) {
    constexpr int NPW = 64 / COUT;  // nodes per wave
    constexpr int M = (HID + 1) * COUT;
    int tid = threadIdx.x;
    int lane = tid & 63;
    int wave = tid >> 6;
    int o = lane % COUT;
    int g = lane / COUT;  // sub-group within wave
    int n = blockIdx.x * (4 * NPW) + wave * NPW + g;
    if (n >= N_NODES) return;
    float w1c[FE];
    float b1k = 0.f;
    if (o < HID) {
        b1k = b1[o];
#pragma unroll
        for (int i = 0; i < FE; i++) w1c[i] = w1[i * HID + o];
    }
    float Pk[HID + 1];
#pragma unroll
    for (int k = 0; k <= HID; k++) Pk[k] = P[(size_t)n * M + k * COUT + o];
    int beg = offs[n], end = offs[n + 1];
    for (int idx = beg; idx < end; idx++) {
        int packed = ebuf[idx];
        int e = packed >> 14;
        int dst = packed & 0x3FFF;
        const float* ear = ea + e * FE;
        float hk = b1k;
#pragma unroll
        for (int i = 0; i < FE; i++) hk += ear[i] * w1c[i];
        hk = fmaxf(hk, 0.f);
        float s = Pk[HID];  // b2 term
#pragma unroll
        for (int k = 0; k < HID; k++) s += __shfl(hk, g * COUT + k) * Pk[k];
        atomicAdd(&agg[dst * COUT + o], s);
    }
}

// --- K4: node update: act = elu(x@root + agg/max(deg,1) + bias); BN sums via
//         per-thread register accumulation + 1 LDS reduce + 256 atomics/chan ---
template <int CIN, int COUT>
__global__ void k_node_update(const float* __restrict__ xin, const float* __restrict__ root,
                              const float* __restrict__ bias, const float* __restrict__ agg,
                              const int* __restrict__ degi, float* __restrict__ act,
                              float* __restrict__ s1g, float* __restrict__ s2g) {
    __shared__ float l1[256], l2[256];
    int tid = threadIdx.x;
    int o = tid % COUT;  // stride (NU_BLOCKS*256) % COUT == 0 -> channel invariant
    float b = bias[o];
    float rcol[CIN];
#pragma unroll
    for (int i = 0; i < CIN; i++) rcol[i] = root[i * COUT + o];
    float acc1 = 0.f, acc2 = 0.f;
    for (int t = blockIdx.x * 256 + tid; t < N_NODES * COUT; t += NU_BLOCKS * 256) {
        int n = t / COUT;
        float s = b;
        const float* xr = xin + n * CIN;
#pragma unroll
        for (int i = 0; i < CIN; i++) s += xr[i] * rcol[i];
        s += agg[t] / fmaxf((float)degi[n], 1.0f);
        float a = elu_f(s);
        act[t] = a;
        acc1 += a; acc2 += a * a;
    }
    l1[tid] = acc1; l2[tid] = acc2;
    __syncthreads();
    for (int s = 128; s >= COUT; s >>= 1) {
        if (tid < s) { l1[tid] += l1[tid + s]; l2[tid] += l2[tid + s]; }
        __syncthreads();
    }
    if (tid < COUT) { atomicAdd(&s1g[tid], l1[tid]); atomicAdd(&s2g[tid], l2[tid]); }
}

// --- K5: batchnorm (training stats) + elu ---
template <int COUT>
__global__ void k_bn_elu(const float* __restrict__ act, const float* __restrict__ s1g,
                         const float* __restrict__ s2g, const float* __restrict__ gamma,
                         const float* __restrict__ beta, float* __restrict__ out) {
    int t = blockIdx.x * blockDim.x + threadIdx.x;
    if (t >= N_NODES * COUT) return;
    int o = t % COUT;
    float m = s1g[o] * (1.0f / N_NODES);
    float v = s2g[o] * (1.0f / N_NODES) - m * m;
    float x = (act[t] - m) * rsqrtf(v + 1e-5f) * gamma[o] + beta[o];
    out[t] = elu_f(x);
}

// --- K6: fc1 (64->128) + elu + fc2 (128->1) + elu + per-block partial sums. ---
__global__ void k_fc_sum(const float* __restrict__ h2, const float* __restrict__ fc1w,
                         const float* __restrict__ fc1b, const float* __restrict__ fc2w,
                         const float* __restrict__ fc2b, float* __restrict__ partial) {
    int tid = threadIdx.x;
    int lane = tid & 63;
    int wave = tid >> 6;
    float b0 = fc1b[lane], b1 = fc1b[lane + 64];
    float w0 = fc2w[lane], w1 = fc2w[lane + 64];
    float fb = fc2b[0];
    float acc = 0.f;
    for (int n = blockIdx.x * 4 + wave; n < N_NODES; n += FC_BLOCKS * 4) {
        const float* hr = h2 + n * C2;
        float s0 = b0, s1 = b1;
#pragma unroll
        for (int i = 0; i < C2; i++) {
            float hv = hr[i];  // broadcast within wave
            s0 += hv * fc1w[i * 128 + lane];
            s1 += hv * fc1w[i * 128 + 64 + lane];
        }
        float v = elu_f(s0) * w0 + elu_f(s1) * w1;
#pragma unroll
        for (int off = 32; off > 0; off >>= 1) v += __shfl_down(v, off);
        if (lane == 0) acc += elu_f(v + fb);
    }
    __shared__ float lds[4];
    if (lane == 0) lds[wave] = acc;
    __syncthreads();
    if (tid == 0) partial[blockIdx.x] = lds[0] + lds[1] + lds[2] + lds[3];
}

// --- K7: final reduction of FC_BLOCKS partials -> out[0] ---
__global__ void k_fc_reduce(const float* __restrict__ partial, float* __restrict__ out) {
    __shared__ float lds[256];
    int tid = threadIdx.x;
    float s = 0.f;
    for (int i = tid; i < FC_BLOCKS; i += 256) s += partial[i];
    lds[tid] = s;
    __syncthreads();
    for (int k = 128; k > 0; k >>= 1) {
        if (tid < k) lds[tid] += lds[tid + k];
        __syncthreads();
    }
    if (tid == 0) out[0] = lds[0];
}

extern "C" void kernel_launch(void* const* d_in, const int* in_sizes, int n_in,
                              void* d_out, int out_size, void* d_ws, size_t ws_size,
                              hipStream_t stream) {
    const float* x        = (const float*)d_in[0];
    const int*   ei       = (const int*)d_in[1];
    const float* ea       = (const float*)d_in[2];
    const float* nn1_w1   = (const float*)d_in[3];
    const float* nn1_b1   = (const float*)d_in[4];
    const float* nn1_w2   = (const float*)d_in[5];
    const float* nn1_b2   = (const float*)d_in[6];
    const float* c1_root  = (const float*)d_in[7];
    const float* c1_bias  = (const float*)d_in[8];
    const float* bn1_g    = (const float*)d_in[9];
    const float* bn1_b    = (const float*)d_in[10];
    const float* nn2_w1   = (const float*)d_in[11];
    const float* nn2_b1   = (const float*)d_in[12];
    const float* nn2_w2   = (const float*)d_in[13];
    const float* nn2_b2   = (const float*)d_in[14];
    const float* c2_root  = (const float*)d_in[15];
    const float* c2_bias  = (const float*)d_in[16];
    const float* bn2_g    = (const float*)d_in[17];
    const float* bn2_b    = (const float*)d_in[18];
    const float* fc1_w    = (const float*)d_in[19];
    const float* fc1_b    = (const float*)d_in[20];
    const float* fc2_w    = (const float*)d_in[21];
    const float* fc2_b    = (const float*)d_in[22];
    float* out = (float*)d_out;

    char* ws = (char*)d_ws;
    size_t off = 0;
    auto alloc = [&](size_t nelem) -> void* {
        void* p = (void*)(ws + off);
        off += nelem * 4;
        off = (off + 255) & ~(size_t)255;
        return p;
    };
    // zeroed region (cnt_src, cnt_dst, agg1, agg2, BN sums) must be first
    int*   cnt_src = (int*)alloc(N_NODES);
    int*   cnt_dst = (int*)alloc(N_NODES);
    float* agg1    = (float*)alloc((size_t)N_NODES * C1);
    float* agg2    = (float*)alloc((size_t)N_NODES * C2);
    float* bn1_s1  = (float*)alloc(C1);
    float* bn1_s2  = (float*)alloc(C1);
    float* bn2_s1  = (float*)alloc(C2);
    float* bn2_s2  = (float*)alloc(C2);
    size_t zero_bytes = off;
    int*   offs    = (int*)alloc(N_NODES + 1);
    int*   cursor  = (int*)alloc(N_NODES);
    int*   ebuf    = (int*)alloc(N_EDGES);
    float* P1      = (float*)alloc((size_t)N_NODES * (HID + 1) * C1);
    float* P2      = (float*)alloc((size_t)N_NODES * (HID + 1) * C2);
    float* a1      = (float*)alloc((size_t)N_NODES * C1);
    float* h1      = (float*)alloc((size_t)N_NODES * C1);
    float* a2      = (float*)alloc((size_t)N_NODES * C2);
    float* h2      = (float*)alloc((size_t)N_NODES * C2);
    float* partial = (float*)alloc(FC_BLOCKS);
    float* wcat1   = (float*)alloc((HID + 1) * FN * C1);
    float* wcat2   = (float*)alloc((HID + 1) * C1 * C2);
    (void)ws_size;

    hipMemsetAsync(d_ws, 0, zero_bytes, stream);
    // wcat = [w2 | b2] so precompute is branch-free
    hipMemcpyAsync(wcat1, nn1_w2, sizeof(float) * HID * FN * C1, hipMemcpyDeviceToDevice, stream);
    hipMemcpyAsync(wcat1 + HID * FN * C1, nn1_b2, sizeof(float) * FN * C1, hipMemcpyDeviceToDevice, stream);
    hipMemcpyAsync(wcat2, nn2_w2, sizeof(float) * HID * C1 * C2, hipMemcpyDeviceToDevice, stream);
    hipMemcpyAsync(wcat2 + HID * C1 * C2, nn2_b2, sizeof(float) * C1 * C2, hipMemcpyDeviceToDevice, stream);

    // ---- CSR build (by src) + dst degree ----
    k_count<<<(N_EDGES + 255) / 256, 256, 0, stream>>>(ei, cnt_src, cnt_dst);
    k_scan<<<1, 1024, 0, stream>>>(cnt_src, offs, cursor);
    k_scatter<<<(N_EDGES + 255) / 256, 256, 0, stream>>>(ei, cursor, ebuf);

    // ---- conv1 ----
    k_precompute<FN, C1, 50><<<((HID + 1) * C1 + 255) / 256 * (N_NODES / 50), 256, 0, stream>>>(x, wcat1, P1);
    k_msg_grouped<C1><<<(N_NODES + 7) / 8, 256, 0, stream>>>(P1, ea, nn1_w1, nn1_b1, offs, ebuf, agg1);
    k_node_update<FN, C1><<<NU_BLOCKS, 256, 0, stream>>>(x, c1_root, c1_bias, agg1,
                                                         cnt_dst, a1, bn1_s1, bn1_s2);
    k_bn_elu<C1><<<(N_NODES * C1) / 256, 256, 0, stream>>>(a1, bn1_s1, bn1_s2, bn1_g, bn1_b, h1);
    // ---- conv2 ----
    k_precompute<C1, C2, 50><<<((HID + 1) * C2 + 255) / 256 * (N_NODES / 50), 256, 0, stream>>>(h1, wcat2, P2);
    k_msg_grouped<C2><<<(N_NODES + 3) / 4, 256, 0, stream>>>(P2, ea, nn2_w1, nn2_b1, offs, ebuf, agg2);
    k_node_update<C1, C2><<<NU_BLOCKS, 256, 0, stream>>>(h1, c2_root, c2_bias, agg2,
                                                         cnt_dst, a2, bn2_s1, bn2_s2);
    k_bn_elu<C2><<<(N_NODES * C2) / 256, 256, 0, stream>>>(a2, bn2_s1, bn2_s2, bn2_g, bn2_b, h2);
    // ---- fc + global sum ----
    k_fc_sum<<<FC_BLOCKS, 256, 0, stream>>>(h2, fc1_w, fc1_b, fc2_w, fc2_b, partial);
    k_fc_reduce<<<1, 256, 0, stream>>>(partial, out);
}

// Round 7
// 274.212 us; speedup vs baseline: 2.0972x; 1.1172x over previous
//
#include <hip/hip_runtime.h>
#include <hip/hip_bf16.h>

#define N_NODES 10000
#define N_EDGES 80000
#define FN 16
#define FE 8
#define HID 25
#define C1 32
#define C2 64
#define NU_BLOCKS 256
#define FC_BLOCKS 640
#define HROW 32  // padded h row (25 used)

__device__ __forceinline__ float elu_f(float x) { return x > 0.f ? x : (expf(x) - 1.f); }

// --- K0a: int histogram of src (CSR build) and dst (mean-agg degree) ---
__global__ void k_count(const int* __restrict__ ei, int* __restrict__ cnt_src,
                        int* __restrict__ cnt_dst) {
    int e = blockIdx.x * 256 + threadIdx.x;
    if (e >= N_EDGES) return;
    atomicAdd(&cnt_src[ei[e]], 1);
    atomicAdd(&cnt_dst[ei[N_EDGES + e]], 1);
}

// --- K0b: exclusive prefix sum over cnt_src (10000) -> offs[10001], cursor copy. ---
__global__ void k_scan(const int* __restrict__ cnt, int* __restrict__ offs,
                       int* __restrict__ cursor) {
    __shared__ int lws[16];
    int tid = threadIdx.x;
    int base = tid * 10;
    int loc[10];
    int s = 0;
#pragma unroll
    for (int j = 0; j < 10; j++) {
        loc[j] = s;
        int c = (base + j < N_NODES) ? cnt[base + j] : 0;
        s += c;
    }
    int lane = tid & 63, wv = tid >> 6;
    int v = s;
    for (int d = 1; d < 64; d <<= 1) {
        int t = __shfl_up(v, d);
        if (lane >= d) v += t;
    }
    if (lane == 63) lws[wv] = v;
    __syncthreads();
    if (tid < 64) {
        int w = (tid < 16) ? lws[tid] : 0;
        for (int d = 1; d < 16; d <<= 1) {
            int t = __shfl_up(w, d);
            if (tid >= d) w += t;
        }
        if (tid < 16) lws[tid] = w;
    }
    __syncthreads();
    int waveoff = (wv > 0) ? lws[wv - 1] : 0;
    int excl = waveoff + v - s;
#pragma unroll
    for (int j = 0; j < 10; j++) {
        int idx = base + j;
        if (idx < N_NODES) { int val = excl + loc[j]; offs[idx] = val; cursor[idx] = val; }
    }
    if (tid == 0) offs[N_NODES] = N_EDGES;
}

// --- K1: scatter edges into src buckets AND compute both convs' edge-MLP hidden
//         relu(ea@w1+b1), stored CSR-position-indexed h[pos][HROW]. ebuf[pos]=dst. ---
__global__ void k_scatter_hidden(const float* __restrict__ ea, const int* __restrict__ ei,
                                 const float* __restrict__ w1a, const float* __restrict__ b1a,
                                 const float* __restrict__ w1b, const float* __restrict__ b1b,
                                 int* __restrict__ cursor, int* __restrict__ ebuf,
                                 float* __restrict__ h1r, float* __restrict__ h2r) {
    __shared__ float sw1a[FE * HID], sw1b[FE * HID], sb1a[HID], sb1b[HID];
    int tid = threadIdx.x;
    for (int i = tid; i < FE * HID; i += 256) { sw1a[i] = w1a[i]; sw1b[i] = w1b[i]; }
    if (tid < HID) { sb1a[tid] = b1a[tid]; sb1b[tid] = b1b[tid]; }
    __syncthreads();
    int e = blockIdx.x * 256 + tid;
    if (e >= N_EDGES) return;
    float a[FE];
#pragma unroll
    for (int i = 0; i < FE; i++) a[i] = ea[e * FE + i];
    int src = ei[e], dst = ei[N_EDGES + e];
    int pos = atomicAdd(&cursor[src], 1);
    ebuf[pos] = dst;
    float* h1p = h1r + (size_t)pos * HROW;
    float* h2p = h2r + (size_t)pos * HROW;
#pragma unroll
    for (int k = 0; k < HID; k++) {
        float s1 = sb1a[k], s2 = sb1b[k];
#pragma unroll
        for (int i = 0; i < FE; i++) { s1 += a[i] * sw1a[i * HID + k]; s2 += a[i] * sw1b[i * HID + k]; }
        h1p[k] = fmaxf(s1, 0.f);
        h2p[k] = fmaxf(s2, 0.f);
    }
}

// --- K2: per-node precompute, m-major, no LDS. P[n,k*COUT+o]=sum_i x[n,i]*w2[k,i,o];
//         row k==HID is the b2 term. wreg loaded once per thread. ---
template <int CIN, int COUT, int TNODES>
__global__ void k_precompute(const float* __restrict__ xin, const float* __restrict__ w2,
                             const float* __restrict__ b2, float* __restrict__ P) {
    constexpr int M = (HID + 1) * COUT;
    constexpr int MB = (M + 255) / 256;
    int tid = threadIdx.x;
    int mb = blockIdx.x % MB;
    int n0 = (blockIdx.x / MB) * TNODES;
    int m = mb * 256 + tid;
    if (m >= M) return;
    int k = m / COUT, o = m % COUT;
    float wreg[CIN];
    if (k < HID) {
#pragma unroll
        for (int i = 0; i < CIN; i++) wreg[i] = w2[(size_t)(k * CIN + i) * COUT + o];
    } else {
#pragma unroll
        for (int i = 0; i < CIN; i++) wreg[i] = b2[i * COUT + o];
    }
    for (int n = n0; n < n0 + TNODES; n++) {
        const float* xr = xin + (size_t)n * CIN;
        float s = 0.f;
#pragma unroll
        for (int i = 0; i < CIN; i++) s += xr[i] * wreg[i];
        P[(size_t)n * M + m] = s;
    }
}

// --- K3a: conv2 message pass. One wave per node; lane = out channel.
//         Node index forced scalar -> offs/ebuf/h rows become s_load;
//         inner loop = 26 v_fmac(v,s,v) + coalesced atomic. 2-edge unroll. ---
__global__ void k_msg_c2(const float* __restrict__ P, const int* __restrict__ offs,
                         const int* __restrict__ ebuf, const float* __restrict__ h2r,
                         float* __restrict__ agg) {
    constexpr int M = (HID + 1) * C2;
    int lane = threadIdx.x & 63;
    int n = __builtin_amdgcn_readfirstlane(blockIdx.x * 4 + (threadIdx.x >> 6));
    if (n >= N_NODES) return;
    const float* Pr = P + (size_t)n * M;
    float Pk[HID + 1];
#pragma unroll
    for (int k = 0; k <= HID; k++) Pk[k] = Pr[k * C2 + lane];
    int beg = offs[n], end = offs[n + 1];
    int idx = beg;
    for (; idx + 1 < end; idx += 2) {
        int d0 = ebuf[idx], d1 = ebuf[idx + 1];
        const float* h0 = h2r + (size_t)idx * HROW;
        const float* h1 = h2r + (size_t)(idx + 1) * HROW;
        float s0 = Pk[HID], s1 = Pk[HID];
#pragma unroll
        for (int k = 0; k < HID; k++) { s0 += h0[k] * Pk[k]; s1 += h1[k] * Pk[k]; }
        atomicAdd(&agg[d0 * C2 + lane], s0);
        atomicAdd(&agg[d1 * C2 + lane], s1);
    }
    if (idx < end) {
        int d0 = ebuf[idx];
        const float* h0 = h2r + (size_t)idx * HROW;
        float s0 = Pk[HID];
#pragma unroll
        for (int k = 0; k < HID; k++) s0 += h0[k] * Pk[k];
        atomicAdd(&agg[d0 * C2 + lane], s0);
    }
}

// --- K3b: conv1 message pass. One wave per node; paired edges: lanes 0-31 =
//         edge i, lanes 32-63 = edge i+1 (same node -> same Pk). ---
__global__ void k_msg_c1(const float* __restrict__ P, const int* __restrict__ offs,
                         const int* __restrict__ ebuf, const float* __restrict__ h1r,
                         float* __restrict__ agg) {
    constexpr int M = (HID + 1) * C1;
    int lane = threadIdx.x & 63;
    int o = lane & 31;
    int n = __builtin_amdgcn_readfirstlane(blockIdx.x * 4 + (threadIdx.x >> 6));
    if (n >= N_NODES) return;
    const float* Pr = P + (size_t)n * M;
    float Pk[HID + 1];
#pragma unroll
    for (int k = 0; k <= HID; k++) Pk[k] = Pr[k * C1 + o];
    int beg = offs[n], end = offs[n + 1];
    int idx = beg;
    for (; idx + 1 < end; idx += 2) {
        int d0 = ebuf[idx], d1 = ebuf[idx + 1];
        const float* h0 = h1r + (size_t)idx * HROW;
        const float* h1 = h1r + (size_t)(idx + 1) * HROW;
        float s0 = Pk[HID], s1 = Pk[HID];
#pragma unroll
        for (int k = 0; k < HID; k++) { s0 += h0[k] * Pk[k]; s1 += h1[k] * Pk[k]; }
        float val = (lane < 32) ? s0 : s1;
        int dsel = (lane < 32) ? d0 : d1;
        atomicAdd(&agg[dsel * C1 + o], val);
    }
    if (idx < end) {
        int d0 = ebuf[idx];
        const float* h0 = h1r + (size_t)idx * HROW;
        float s0 = Pk[HID];
#pragma unroll
        for (int k = 0; k < HID; k++) s0 += h0[k] * Pk[k];
        if (lane < 32) atomicAdd(&agg[d0 * C1 + o], s0);
    }
}

// --- K4: node update: act = elu(x@root + agg/max(deg,1) + bias); BN sums via
//         per-thread register accumulation + 1 LDS reduce + 256 atomics/chan ---
template <int CIN, int COUT>
__global__ void k_node_update(const float* __restrict__ xin, const float* __restrict__ root,
                              const float* __restrict__ bias, const float* __restrict__ agg,
                              const int* __restrict__ degi, float* __restrict__ act,
                              float* __restrict__ s1g, float* __restrict__ s2g) {
    __shared__ float l1[256], l2[256];
    int tid = threadIdx.x;
    int o = tid % COUT;
    float b = bias[o];
    float rcol[CIN];
#pragma unroll
    for (int i = 0; i < CIN; i++) rcol[i] = root[i * COUT + o];
    float acc1 = 0.f, acc2 = 0.f;
    for (int t = blockIdx.x * 256 + tid; t < N_NODES * COUT; t += NU_BLOCKS * 256) {
        int n = t / COUT;
        float s = b;
        const float* xr = xin + n * CIN;
#pragma unroll
        for (int i = 0; i < CIN; i++) s += xr[i] * rcol[i];
        s += agg[t] / fmaxf((float)degi[n], 1.0f);
        float a = elu_f(s);
        act[t] = a;
        acc1 += a; acc2 += a * a;
    }
    l1[tid] = acc1; l2[tid] = acc2;
    __syncthreads();
    for (int s = 128; s >= COUT; s >>= 1) {
        if (tid < s) { l1[tid] += l1[tid + s]; l2[tid] += l2[tid + s]; }
        __syncthreads();
    }
    if (tid < COUT) { atomicAdd(&s1g[tid], l1[tid]); atomicAdd(&s2g[tid], l2[tid]); }
}

// --- K5: batchnorm (training stats) + elu ---
template <int COUT>
__global__ void k_bn_elu(const float* __restrict__ act, const float* __restrict__ s1g,
                         const float* __restrict__ s2g, const float* __restrict__ gamma,
                         const float* __restrict__ beta, float* __restrict__ out) {
    int t = blockIdx.x * blockDim.x + threadIdx.x;
    if (t >= N_NODES * COUT) return;
    int o = t % COUT;
    float m = s1g[o] * (1.0f / N_NODES);
    float v = s2g[o] * (1.0f / N_NODES) - m * m;
    float x = (act[t] - m) * rsqrtf(v + 1e-5f) * gamma[o] + beta[o];
    out[t] = elu_f(x);
}

// --- K6: fc1 (64->128) + elu + fc2 (128->1) + elu + per-block partial sums. ---
__global__ void k_fc_sum(const float* __restrict__ h2, const float* __restrict__ fc1w,
                         const float* __restrict__ fc1b, const float* __restrict__ fc2w,
                         const float* __restrict__ fc2b, float* __restrict__ partial) {
    int tid = threadIdx.x;
    int lane = tid & 63;
    int wave = tid >> 6;
    float b0 = fc1b[lane], b1 = fc1b[lane + 64];
    float w0 = fc2w[lane], w1 = fc2w[lane + 64];
    float fb = fc2b[0];
    float acc = 0.f;
    for (int n = blockIdx.x * 4 + wave; n < N_NODES; n += FC_BLOCKS * 4) {
        int ns = __builtin_amdgcn_readfirstlane(n);
        const float* hr = h2 + (size_t)ns * C2;
        float s0 = b0, s1 = b1;
#pragma unroll
        for (int i = 0; i < C2; i++) {
            float hv = hr[i];
            s0 += hv * fc1w[i * 128 + lane];
            s1 += hv * fc1w[i * 128 + 64 + lane];
        }
        float v = elu_f(s0) * w0 + elu_f(s1) * w1;
#pragma unroll
        for (int off = 32; off > 0; off >>= 1) v += __shfl_down(v, off);
        if (lane == 0) acc += elu_f(v + fb);
    }
    __shared__ float lds[4];
    if (lane == 0) lds[wave] = acc;
    __syncthreads();
    if (tid == 0) partial[blockIdx.x] = lds[0] + lds[1] + lds[2] + lds[3];
}

// --- K7: final reduction of FC_BLOCKS partials -> out[0] ---
__global__ void k_fc_reduce(const float* __restrict__ partial, float* __restrict__ out) {
    __shared__ float lds[256];
    int tid = threadIdx.x;
    float s = 0.f;
    for (int i = tid; i < FC_BLOCKS; i += 256) s += partial[i];
    lds[tid] = s;
    __syncthreads();
    for (int k = 128; k > 0; k >>= 1) {
        if (tid < k) lds[tid] += lds[tid + k];
        __syncthreads();
    }
    if (tid == 0) out[0] = lds[0];
}

extern "C" void kernel_launch(void* const* d_in, const int* in_sizes, int n_in,
                              void* d_out, int out_size, void* d_ws, size_t ws_size,
                              hipStream_t stream) {
    const float* x        = (const float*)d_in[0];
    const int*   ei       = (const int*)d_in[1];
    const float* ea       = (const float*)d_in[2];
    const float* nn1_w1   = (const float*)d_in[3];
    const float* nn1_b1   = (const float*)d_in[4];
    const float* nn1_w2   = (const float*)d_in[5];
    const float* nn1_b2   = (const float*)d_in[6];
    const float* c1_root  = (const float*)d_in[7];
    const float* c1_bias  = (const float*)d_in[8];
    const float* bn1_g    = (const float*)d_in[9];
    const float* bn1_b    = (const float*)d_in[10];
    const float* nn2_w1   = (const float*)d_in[11];
    const float* nn2_b1   = (const float*)d_in[12];
    const float* nn2_w2   = (const float*)d_in[13];
    const float* nn2_b2   = (const float*)d_in[14];
    const float* c2_root  = (const float*)d_in[15];
    const float* c2_bias  = (const float*)d_in[16];
    const float* bn2_g    = (const float*)d_in[17];
    const float* bn2_b    = (const float*)d_in[18];
    const float* fc1_w    = (const float*)d_in[19];
    const float* fc1_b    = (const float*)d_in[20];
    const float* fc2_w    = (const float*)d_in[21];
    const float* fc2_b    = (const float*)d_in[22];
    float* out = (float*)d_out;

    char* ws = (char*)d_ws;
    size_t off = 0;
    auto alloc = [&](size_t nelem) -> void* {
        void* p = (void*)(ws + off);
        off += nelem * 4;
        off = (off + 255) & ~(size_t)255;
        return p;
    };
    // zeroed region (cnt_src, cnt_dst, agg1, agg2, BN sums) must be first
    int*   cnt_src = (int*)alloc(N_NODES);
    int*   cnt_dst = (int*)alloc(N_NODES);
    float* agg1    = (float*)alloc((size_t)N_NODES * C1);
    float* agg2    = (float*)alloc((size_t)N_NODES * C2);
    float* bn1_s1  = (float*)alloc(C1);
    float* bn1_s2  = (float*)alloc(C1);
    float* bn2_s1  = (float*)alloc(C2);
    float* bn2_s2  = (float*)alloc(C2);
    size_t zero_bytes = off;
    int*   offs    = (int*)alloc(N_NODES + 1);
    int*   cursor  = (int*)alloc(N_NODES);
    int*   ebuf    = (int*)alloc(N_EDGES);
    float* h1r     = (float*)alloc((size_t)N_EDGES * HROW);
    float* h2r     = (float*)alloc((size_t)N_EDGES * HROW);
    float* P1      = (float*)alloc((size_t)N_NODES * (HID + 1) * C1);
    float* P2      = (float*)alloc((size_t)N_NODES * (HID + 1) * C2);
    float* a1      = (float*)alloc((size_t)N_NODES * C1);
    float* h1      = (float*)alloc((size_t)N_NODES * C1);
    float* a2      = (float*)alloc((size_t)N_NODES * C2);
    float* h2      = (float*)alloc((size_t)N_NODES * C2);
    float* partial = (float*)alloc(FC_BLOCKS);
    (void)ws_size;

    hipMemsetAsync(d_ws, 0, zero_bytes, stream);

    // ---- CSR build (by src) + dst degree + edge-MLP hidden for both convs ----
    k_count<<<(N_EDGES + 255) / 256, 256, 0, stream>>>(ei, cnt_src, cnt_dst);
    k_scan<<<1, 1024, 0, stream>>>(cnt_src, offs, cursor);
    k_scatter_hidden<<<(N_EDGES + 255) / 256, 256, 0, stream>>>(ea, ei, nn1_w1, nn1_b1,
                                                                nn2_w1, nn2_b1, cursor, ebuf,
                                                                h1r, h2r);
    // ---- conv1 ----
    k_precompute<FN, C1, 50><<<(((HID + 1) * C1 + 255) / 256) * (N_NODES / 50), 256, 0, stream>>>(x, nn1_w2, nn1_b2, P1);
    k_msg_c1<<<(N_NODES + 3) / 4, 256, 0, stream>>>(P1, offs, ebuf, h1r, agg1);
    k_node_update<FN, C1><<<NU_BLOCKS, 256, 0, stream>>>(x, c1_root, c1_bias, agg1,
                                                         cnt_dst, a1, bn1_s1, bn1_s2);
    k_bn_elu<C1><<<(N_NODES * C1) / 256, 256, 0, stream>>>(a1, bn1_s1, bn1_s2, bn1_g, bn1_b, h1);
    // ---- conv2 ----
    k_precompute<C1, C2, 50><<<(((HID + 1) * C2 + 255) / 256) * (N_NODES / 50), 256, 0, stream>>>(h1, nn2_w2, nn2_b2, P2);
    k_msg_c2<<<(N_NODES + 3) / 4, 256, 0, stream>>>(P2, offs, ebuf, h2r, agg2);
    k_node_update<C1, C2><<<NU_BLOCKS, 256, 0, stream>>>(h1, c2_root, c2_bias, agg2,
                                                         cnt_dst, a2, bn2_s1, bn2_s2);
    k_bn_elu<C2><<<(N_NODES * C2) / 256, 256, 0, stream>>>(a2, bn2_s1, bn2_s2, bn2_g, bn2_b, h2);
    // ---- fc + global sum ----
    k_fc_sum<<<FC_BLOCKS, 256, 0, stream>>>(h2, fc1_w, fc1_b, fc2_w, fc2_b, partial);
    k_fc_reduce<<<1, 256, 0, stream>>>(partial, out);
}